// Round 7
// baseline (135.398 us; speedup 1.0000x reference)
//
#include <hip/hip_runtime.h>

#define NN 50000
#define NE 800000
#define NB 64
#define DIM 64
#define TM 128
#define CAP 128   // per-node CSR capacity. deg ~ Poisson(16), max over 50k nodes ~40.

typedef float vfloat4 __attribute__((ext_vector_type(4)));

// ws layout: cursor/deg NN ints | eids NN*CAP ints | U1 NB*DIM f32 | ve NN*DIM f32

__global__ __launch_bounds__(256) void zero_k(int4* __restrict__ p, int n4) {
    int i = blockIdx.x * 256 + threadIdx.x;
    if (i < n4) p[i] = make_int4(0, 0, 0, 0);
}

// one edge per thread (max TLP to hide atomic-return latency);
// blocks 0..63 also premix U1 = u@W1u + b1
__global__ __launch_bounds__(256) void fill_k(const int* __restrict__ src,
                                              int* __restrict__ cursor,
                                              int* __restrict__ eids,
                                              const float* __restrict__ u,
                                              const float* __restrict__ W1,
                                              const float* __restrict__ b1,
                                              float* __restrict__ U1) {
    int t = blockIdx.x * 256 + threadIdx.x;   // grid exactly NE threads
    if (t < NE) {
        int s = src[t];
        int pos = atomicAdd(&cursor[s], 1);
        eids[s * CAP + pos] = t;              // store is posted; no wait
    }
    if (blockIdx.x < NB && threadIdx.x < DIM) {
        int b = blockIdx.x, jj = threadIdx.x;
        float a = b1[jj];
        const float* up = u + b * DIM;
        #pragma unroll 8
        for (int k = 0; k < DIM; ++k)
            a = fmaf(up[k], W1[(2 * DIM + k) * DIM + jj], a);
        U1[b * DIM + jj] = a;
    }
}

// one wave per node; 4 edge slots x 16 float4 chunks; unconditional clamped gathers.
__global__ __launch_bounds__(256) void reduce_k(const int* __restrict__ deg_arr,
                                                const int* __restrict__ eids,
                                                const vfloat4* __restrict__ ea4,
                                                float4* __restrict__ ve4) {
    int n = (blockIdx.x * 256 + threadIdx.x) >> 6;   // grid exactly NN*64 threads
    int lane = threadIdx.x & 63;
    int chunk = lane & 15, slot = lane >> 4;
    int deg = deg_arr[n];
    const int* ebase = eids + (size_t)n * CAP;

    vfloat4 acc = {0.f, 0.f, 0.f, 0.f};
    const vfloat4 vzero = {0.f, 0.f, 0.f, 0.f};

    if (deg > 0) {
        int dm1 = deg - 1;
        int e[8];
        #pragma unroll
        for (int r = 0; r < 8; ++r) {
            int j = slot + r * 4;
            e[r] = ebase[j < dm1 ? j : dm1];
        }
        #pragma unroll
        for (int r = 0; r < 8; ++r) {
            vfloat4 v = __builtin_nontemporal_load(&ea4[(size_t)e[r] * 16 + chunk]);
            acc += (slot + r * 4 < deg) ? v : vzero;
        }
        for (int j = 32 + slot; j < deg; j += 4) {   // rare tail: deg > 32
            int ee = ebase[j];
            vfloat4 v = __builtin_nontemporal_load(&ea4[(size_t)ee * 16 + chunk]);
            acc += v;
        }
    }

    #pragma unroll
    for (int m = 16; m <= 32; m <<= 1) {
        acc.x += __shfl_xor(acc.x, m, 64);
        acc.y += __shfl_xor(acc.y, m, 64);
        acc.z += __shfl_xor(acc.z, m, 64);
        acc.w += __shfl_xor(acc.w, m, 64);
    }
    if (slot == 0) {
        float rs = 1.0f / fmaxf((float)deg, 1.0f);
        ve4[(size_t)n * 16 + chunk] = make_float4(acc.x * rs, acc.y * rs, acc.z * rs, acc.w * rs);
    }
}

#define LDA 132  // padded row stride for A tile

// 512-thread variant: each thread computes 4 nodes x 4 dims
__device__ __forceinline__ void gemm4(float acc[4][4],
                                      const float* __restrict__ A,
                                      const float* __restrict__ Wb,
                                      int NG, int DG) {
    #pragma unroll 4
    for (int k = 0; k < 64; ++k) {
        const float4 w = *(const float4*)&Wb[k * 64 + DG];
        const float4 a = *(const float4*)&A[k * LDA + NG];
        const float av[4] = {a.x, a.y, a.z, a.w};
        const float wv[4] = {w.x, w.y, w.z, w.w};
        #pragma unroll
        for (int i = 0; i < 4; ++i)
            #pragma unroll
            for (int j = 0; j < 4; ++j)
                acc[i][j] = fmaf(av[i], wv[j], acc[i][j]);
    }
}

__global__ __launch_bounds__(512) void mlp_k(const float* __restrict__ x,
                                             const int* __restrict__ batch,
                                             const float* __restrict__ W1,
                                             const float* __restrict__ W2,
                                             const float* __restrict__ b2,
                                             const float* __restrict__ ve,
                                             const float* __restrict__ U1,
                                             float* __restrict__ out) {
    __shared__ float A[64 * LDA];
    __shared__ float Wb[64 * 64];

    const int t = threadIdx.x;        // 0..511
    const int c = t & 15;             // staging k-chunk
    const int rb = t >> 4;            // 0..31
    const int DG = (t & 15) * 4;      // 4 output dims
    const int NG = (t >> 4) * 4;      // 4 local nodes
    const int n0 = blockIdx.x * TM;

    float acc[4][4];

    #pragma unroll
    for (int i = 0; i < 4; ++i) {
        int n = n0 + NG + i;
        int b = (n < NN) ? batch[n] : 0;
        const float4 uv = *(const float4*)&U1[b * DIM + DG];
        acc[i][0] = uv.x; acc[i][1] = uv.y; acc[i][2] = uv.z; acc[i][3] = uv.w;
    }

    // ---------- pass 1: x @ W1[0:64] ----------
    #pragma unroll
    for (int it = 0; it < 4; ++it) {
        int r = rb + it * 32;
        int n = n0 + r;
        float4 v = make_float4(0.f, 0.f, 0.f, 0.f);
        if (n < NN) v = *(const float4*)&x[(size_t)n * DIM + c * 4];
        A[(c * 4 + 0) * LDA + r] = v.x;
        A[(c * 4 + 1) * LDA + r] = v.y;
        A[(c * 4 + 2) * LDA + r] = v.z;
        A[(c * 4 + 3) * LDA + r] = v.w;
    }
    #pragma unroll
    for (int it = 0; it < 2; ++it) {
        int r = rb + it * 32;
        *(float4*)&Wb[r * 64 + c * 4] = *(const float4*)&W1[(size_t)r * DIM + c * 4];
    }
    __syncthreads();
    gemm4(acc, A, Wb, NG, DG);
    __syncthreads();

    // ---------- pass 2: v_e @ W1[64:128] ----------
    #pragma unroll
    for (int it = 0; it < 4; ++it) {
        int r = rb + it * 32;
        int n = n0 + r;
        float4 v = make_float4(0.f, 0.f, 0.f, 0.f);
        if (n < NN) v = *(const float4*)&ve[(size_t)n * DIM + c * 4];
        A[(c * 4 + 0) * LDA + r] = v.x;
        A[(c * 4 + 1) * LDA + r] = v.y;
        A[(c * 4 + 2) * LDA + r] = v.z;
        A[(c * 4 + 3) * LDA + r] = v.w;
    }
    #pragma unroll
    for (int it = 0; it < 2; ++it) {
        int r = rb + it * 32;
        *(float4*)&Wb[r * 64 + c * 4] = *(const float4*)&W1[(size_t)(64 + r) * DIM + c * 4];
    }
    __syncthreads();
    gemm4(acc, A, Wb, NG, DG);

    #pragma unroll
    for (int i = 0; i < 4; ++i)
        #pragma unroll
        for (int j = 0; j < 4; ++j)
            acc[i][j] = fmaxf(acc[i][j], 0.f);

    __syncthreads();

    // ---------- layer 2: h @ W2 ----------
    #pragma unroll
    for (int j = 0; j < 4; ++j) {
        float4 h = make_float4(acc[0][j], acc[1][j], acc[2][j], acc[3][j]);
        *(float4*)&A[(DG + j) * LDA + NG] = h;
    }
    #pragma unroll
    for (int it = 0; it < 2; ++it) {
        int r = rb + it * 32;
        *(float4*)&Wb[r * 64 + c * 4] = *(const float4*)&W2[(size_t)r * DIM + c * 4];
    }
    __syncthreads();

    {
        const float4 bv = *(const float4*)&b2[DG];
        #pragma unroll
        for (int i = 0; i < 4; ++i) {
            acc[i][0] = bv.x; acc[i][1] = bv.y; acc[i][2] = bv.z; acc[i][3] = bv.w;
        }
    }
    gemm4(acc, A, Wb, NG, DG);

    #pragma unroll
    for (int i = 0; i < 4; ++i) {
        int n = n0 + NG + i;
        if (n < NN) {
            float4 o = make_float4(acc[i][0], acc[i][1], acc[i][2], acc[i][3]);
            *(float4*)&out[(size_t)n * DIM + DG] = o;
        }
    }
}

extern "C" void kernel_launch(void* const* d_in, const int* in_sizes, int n_in,
                              void* d_out, int out_size, void* d_ws, size_t ws_size,
                              hipStream_t stream)
{
    const float* x     = (const float*)d_in[0];
    const int*   eidx  = (const int*)d_in[1];    // [2,E], row 0 = src
    const float* ea    = (const float*)d_in[2];
    const float* u     = (const float*)d_in[3];
    const int*   batch = (const int*)d_in[4];
    const float* W1    = (const float*)d_in[5];
    const float* b1    = (const float*)d_in[6];
    const float* W2    = (const float*)d_in[7];
    const float* b2    = (const float*)d_in[8];
    float* out = (float*)d_out;

    int*   cursor = (int*)d_ws;                        // NN ints (becomes deg)
    int*   eids   = cursor + NN;                       // NN*CAP ints
    float* U1     = (float*)(eids + (size_t)NN * CAP); // NB*DIM floats
    float* ve     = U1 + NB * DIM;                     // NN*DIM floats

    zero_k<<<(NN / 4 + 255) / 256, 256, 0, stream>>>((int4*)cursor, NN / 4);
    fill_k<<<NE / 256, 256, 0, stream>>>(eidx, cursor, eids, u, W1, b1, U1);
    reduce_k<<<(NN * 64) / 256, 256, 0, stream>>>(cursor, eids, (const vfloat4*)ea, (float4*)ve);
    mlp_k<<<(NN + TM - 1) / TM, 512, 0, stream>>>(x, batch, W1, W2, b2, ve, U1, out);
}